// Round 10
// baseline (154.087 us; speedup 1.0000x reference)
//
#include <hip/hip_runtime.h>
#include <math.h>

// SoftMoE fp32: B=4,S=4096,D=768,E=16,SLOTS=1,H=3072
constexpr int B = 4, S = 4096, D = 768, E = 16, N = 16, H = 3072;
constexpr int HL = 96;             // h-chunk in fused FFN
constexpr int NHC = H / HL;        // 32
constexpr int LBLK = 32;           // rows per lx block
constexpr int LPB = S / LBLK;      // lx blocks per b = 128

// workspace layout (float offsets)
constexpr size_t OFF_LOG  = 0;                                   // B*S*N
constexpr size_t OFF_PCM  = OFF_LOG + (size_t)B * S * N;         // B*LPB*N
constexpr size_t OFF_PCS  = OFF_PCM + (size_t)B * LPB * N;       // B*LPB*N
constexpr size_t OFF_CMAX = OFF_PCS + (size_t)B * LPB * N;       // B*N
constexpr size_t OFF_CSUM = OFF_CMAX + (size_t)B * N;            // B*N
constexpr size_t OFF_XSP  = OFF_CSUM + (size_t)B * N;            // B*LPB*N*D
constexpr size_t OFF_XS   = OFF_XSP + (size_t)B * LPB * N * D;   // B*N*D
constexpr size_t OFF_YSP  = OFF_XS + (size_t)B * N * D;          // NHC*B*E*D
constexpr size_t OFF_YS   = OFF_YSP + (size_t)NHC * B * E * D;   // B*E*D

__device__ __forceinline__ void fma4(float4& a, float s, const float4& w) {
    a.x = fmaf(s, w.x, a.x);
    a.y = fmaf(s, w.y, a.y);
    a.z = fmaf(s, w.z, a.z);
    a.w = fmaf(s, w.w, a.w);
}

// ---------------- K1: fused logits + dispatch softmax + xs partials + cstats ----
// grid: B*LPB = 512 blocks, 256 threads. x rows staged ONCE in LDS; dw stays in LDS.
__global__ __launch_bounds__(256) void k_lx(const float* __restrict__ x,
                                            const float* __restrict__ phi,
                                            float* __restrict__ logits,
                                            float* __restrict__ xsp,
                                            float* __restrict__ pcm,
                                            float* __restrict__ pcs) {
    __shared__ float ph[16][D];          // 48 KB
    __shared__ float xr[LBLK][D + 4];    // 96.5 KB (pad 4: groups land on distinct bank quadrants)
    __shared__ float dwl[LBLK][16];      // 2 KB
    __shared__ float rm[16][16], rs[16][16];
    const int t = threadIdx.x;
    const int blk = blockIdx.x;
    const int b = blk / LPB;
    const int s0 = (blk % LPB) * LBLK;

    // stage phi [D][16] -> ph[n][d] transposed
#pragma unroll
    for (int i = 0; i < 12; ++i) {
        const int idx = i * 1024 + t * 4;
        const float4 v = *reinterpret_cast<const float4*>(phi + idx);
        const int d0 = idx >> 4;
        const int n0 = idx & 15;
        ph[n0 + 0][d0] = v.x;
        ph[n0 + 1][d0] = v.y;
        ph[n0 + 2][d0] = v.z;
        ph[n0 + 3][d0] = v.w;
    }
    // stage x rows -> xr (coalesced float4; 6144 float4s, 24/thread)
    const float* xsrc = x + ((size_t)b * S + s0) * D;
#pragma unroll
    for (int i = 0; i < 24; ++i) {
        const int idx = i * 256 + t;          // float4 index over [32][192]
        const int r = idx / 192, c = idx % 192;
        *reinterpret_cast<float4*>(&xr[r][c * 4]) =
            *reinterpret_cast<const float4*>(xsrc + (size_t)idx * 4);
    }
    __syncthreads();

    // logits: 16-lane group handles 2 rows
    const int gid = t >> 4;
    const int ln = t & 15;
    const int r0 = gid * 2, r1 = r0 + 1;

    float4 a0[12], a1[12];
#pragma unroll
    for (int j = 0; j < 12; ++j) {
        a0[j] = *reinterpret_cast<const float4*>(&xr[r0][j * 64 + ln * 4]);
        a1[j] = *reinterpret_cast<const float4*>(&xr[r1][j * 64 + ln * 4]);
    }
    float p0[16], p1[16];
#pragma unroll
    for (int n = 0; n < 16; ++n) {
        float q0 = 0.f, q1 = 0.f;
#pragma unroll
        for (int j = 0; j < 12; ++j) {
            const float4 pv = *reinterpret_cast<const float4*>(&ph[n][j * 64 + ln * 4]);
            q0 = fmaf(a0[j].x, pv.x, q0); q1 = fmaf(a1[j].x, pv.x, q1);
            q0 = fmaf(a0[j].y, pv.y, q0); q1 = fmaf(a1[j].y, pv.y, q1);
            q0 = fmaf(a0[j].z, pv.z, q0); q1 = fmaf(a1[j].z, pv.z, q1);
            q0 = fmaf(a0[j].w, pv.w, q0); q1 = fmaf(a1[j].w, pv.w, q1);
        }
        p0[n] = q0; p1[n] = q1;
    }
#pragma unroll
    for (int m = 1; m < 16; m <<= 1) {
#pragma unroll
        for (int n = 0; n < 16; ++n) {
            p0[n] += __shfl_xor(p0[n], m, 64);
            p1[n] += __shfl_xor(p1[n], m, 64);
        }
    }
    float m0 = -1e30f, m1 = -1e30f;
#pragma unroll
    for (int n = 0; n < 16; ++n) { m0 = fmaxf(m0, p0[n]); m1 = fmaxf(m1, p1[n]); }
    float su0 = 0.f, su1 = 0.f;
#pragma unroll
    for (int n = 0; n < 16; ++n) { su0 += __expf(p0[n] - m0); su1 += __expf(p1[n] - m1); }
    const size_t o0 = ((size_t)b * S + s0 + r0) * N + ln;
    logits[o0] = p0[ln];
    logits[o0 + N] = p1[ln];
    dwl[r0][ln] = __expf(p0[ln] - m0) / su0;
    dwl[r1][ln] = __expf(p1[ln] - m1) / su1;

    const float mm = fmaxf(p0[ln], p1[ln]);
    rm[gid][ln] = mm;
    rs[gid][ln] = __expf(p0[ln] - mm) + __expf(p1[ln] - mm);
    __syncthreads();

    if (t < 16) {  // t = n: LSE-merge 16 group partials -> block partial
        float M = -1e30f;
#pragma unroll
        for (int g = 0; g < 16; ++g) M = fmaxf(M, rm[g][t]);
        float SS = 0.f;
#pragma unroll
        for (int g = 0; g < 16; ++g) SS += rs[g][t] * __expf(rm[g][t] - M);
        pcm[blk * 16 + t] = M;
        pcs[blk * 16 + t] = SS;
    }

    // xs partials for this 32-row chunk (t<192: thread owns 4 d)
    if (t < 192) {
        const int d4 = t * 4;
        float4 a[16];
#pragma unroll
        for (int n = 0; n < 16; ++n) a[n] = float4{0.f, 0.f, 0.f, 0.f};
#pragma unroll 4
        for (int s = 0; s < LBLK; ++s) {
            const float4 xv = *reinterpret_cast<const float4*>(&xr[s][d4]);
#pragma unroll
            for (int n = 0; n < 16; ++n) {
                const float w = dwl[s][n];   // wave-uniform broadcast
                a[n].x = fmaf(w, xv.x, a[n].x);
                a[n].y = fmaf(w, xv.y, a[n].y);
                a[n].z = fmaf(w, xv.z, a[n].z);
                a[n].w = fmaf(w, xv.w, a[n].w);
            }
        }
        float* o = xsp + (size_t)blk * N * D + d4;
#pragma unroll
        for (int n = 0; n < 16; ++n)
            *reinterpret_cast<float4*>(o + (size_t)n * D) = a[n];
    }
}

// ---------------- K2: reduce xs partials + merge combine stats ----------------
// grid: 193 blocks. 0..191: xsred (256 thr). 192: cmerge (t<64).
__global__ __launch_bounds__(256) void k_xsred_cmerge(const float* __restrict__ xsp,
                                                      float* __restrict__ xs,
                                                      const float* __restrict__ pcm,
                                                      const float* __restrict__ pcs,
                                                      float* __restrict__ cmax,
                                                      float* __restrict__ csum) {
    const int t = threadIdx.x;
    if (blockIdx.x < 192) {
        const int i = blockIdx.x * 256 + t;      // over B*N*D
        const int b = i / (N * D);
        const int rem = i % (N * D);
        const float* p = xsp + (size_t)b * LPB * N * D + rem;
        float sum = 0.f;
#pragma unroll 4
        for (int c = 0; c < LPB; ++c) sum += p[(size_t)c * N * D];
        xs[i] = sum;
    } else if (t < 64) {
        const int b = t >> 4, n = t & 15;
        float M = -1e30f;
#pragma unroll 8
        for (int c = 0; c < LPB; ++c) M = fmaxf(M, pcm[((size_t)b * LPB + c) * 16 + n]);
        float SS = 0.f;
#pragma unroll 8
        for (int c = 0; c < LPB; ++c)
            SS += pcs[((size_t)b * LPB + c) * 16 + n] * __expf(pcm[((size_t)b * LPB + c) * 16 + n] - M);
        cmax[b * 16 + n] = M;
        csum[b * 16 + n] = SS;
    }
}

// ---------------- K3: fused FFN, WIDE loads (2 dense float4 streams/thread) ----
// grid: E*NHC = 512 blocks, 384 threads. Block = (e, h-chunk of HL=96).
__global__ __launch_bounds__(384) void k_ffn(const float* __restrict__ xs,
                                             const float* __restrict__ W1,
                                             const float* __restrict__ b1,
                                             const float* __restrict__ W2,
                                             float* __restrict__ ysp) {
    __shared__ __align__(16) float xs_lds[D][4];       // 12 KB
    __shared__ __align__(16) float red[32][HL][4];     // 48 KB (reused as pbuf in phase 2)
    __shared__ __align__(16) float h_lds[HL][4];       // 1.5 KB

    const int t = threadIdx.x;
    const int e = blockIdx.x / NHC;
    const int hc = blockIdx.x % NHC;
    const int h0 = hc * HL;

    // phase 0: stage xs[:, e, :] transposed -> xs_lds[d][b]
    for (int idx = t; idx < D; idx += 384) {
#pragma unroll
        for (int b = 0; b < 4; ++b)
            xs_lds[idx][b] = xs[((size_t)b * N + e) * D + idx];
    }
    __syncthreads();

    // phase 1: q = t/12 (32 d-groups x 24 rows), cg = t%12.
    // Each thread: cols [cg*4, cg*4+4) and [48+cg*4, 48+cg*4+4) -> two DENSE 192B
    // wave-segments per row; 2 independent loads + 32 FMA per iter.
    {
        const int q = t / 12;
        const int cg = t % 12;
        const int c4a = cg * 4, c4b = 48 + cg * 4;
        float4 aA[4], aB[4];
#pragma unroll
        for (int b = 0; b < 4; ++b) { aA[b] = float4{0,0,0,0}; aB[b] = float4{0,0,0,0}; }
        const float* w1p = W1 + ((size_t)e * D + (size_t)q * 24) * H + h0;
#pragma unroll 8
        for (int dd = 0; dd < 24; ++dd) {
            const float* row = w1p + (size_t)dd * H;
            const float4 wa = *reinterpret_cast<const float4*>(row + c4a);
            const float4 wb = *reinterpret_cast<const float4*>(row + c4b);
            const float* xv = &xs_lds[q * 24 + dd][0];
            const float x0 = xv[0], x1 = xv[1], x2 = xv[2], x3 = xv[3];
            fma4(aA[0], x0, wa); fma4(aB[0], x0, wb);
            fma4(aA[1], x1, wa); fma4(aB[1], x1, wb);
            fma4(aA[2], x2, wa); fma4(aB[2], x2, wb);
            fma4(aA[3], x3, wa); fma4(aB[3], x3, wb);
        }
        *reinterpret_cast<float4*>(&red[q][c4a + 0][0]) = float4{aA[0].x, aA[1].x, aA[2].x, aA[3].x};
        *reinterpret_cast<float4*>(&red[q][c4a + 1][0]) = float4{aA[0].y, aA[1].y, aA[2].y, aA[3].y};
        *reinterpret_cast<float4*>(&red[q][c4a + 2][0]) = float4{aA[0].z, aA[1].z, aA[2].z, aA[3].z};
        *reinterpret_cast<float4*>(&red[q][c4a + 3][0]) = float4{aA[0].w, aA[1].w, aA[2].w, aA[3].w};
        *reinterpret_cast<float4*>(&red[q][c4b + 0][0]) = float4{aB[0].x, aB[1].x, aB[2].x, aB[3].x};
        *reinterpret_cast<float4*>(&red[q][c4b + 1][0]) = float4{aB[0].y, aB[1].y, aB[2].y, aB[3].y};
        *reinterpret_cast<float4*>(&red[q][c4b + 2][0]) = float4{aB[0].z, aB[1].z, aB[2].z, aB[3].z};
        *reinterpret_cast<float4*>(&red[q][c4b + 3][0]) = float4{aB[0].w, aB[1].w, aB[2].w, aB[3].w};
    }
    __syncthreads();

    // reduce (all 384 threads): col = t/4, b = t&3; 32-way sum + bias + exact GELU
    {
        const int col = t >> 2, b = t & 3;
        float s = 0.f;
#pragma unroll
        for (int q = 0; q < 32; ++q) s += red[q][col][b];
        s += b1[(size_t)e * H + h0 + col];
        s = 0.5f * s * (1.0f + erff(s * 0.70710678118654752f));
        h_lds[col][b] = s;
    }
    __syncthreads();

    // phase 2: kq = t/96 (4 k-quarters x 24 rows), dg = t%96.
    // Each thread: d-cols [dg*4, +4) and [384+dg*4, +4) -> dense 384B wave-segments.
    const int kq = t / 96;
    const int dg = t % 96;
    const int d4a = dg * 4, d4b = 384 + dg * 4;
    float4 yA[4], yB[4];
#pragma unroll
    for (int b = 0; b < 4; ++b) { yA[b] = float4{0,0,0,0}; yB[b] = float4{0,0,0,0}; }
    {
        const float* w2p = W2 + ((size_t)e * H + h0 + (size_t)kq * 24) * D;
#pragma unroll 8
        for (int kk = 0; kk < 24; ++kk) {
            const float* row = w2p + (size_t)kk * D;
            const float4 wa = *reinterpret_cast<const float4*>(row + d4a);
            const float4 wb = *reinterpret_cast<const float4*>(row + d4b);
            const float* hv = &h_lds[kq * 24 + kk][0];
            fma4(yA[0], hv[0], wa); fma4(yB[0], hv[0], wb);
            fma4(yA[1], hv[1], wa); fma4(yB[1], hv[1], wb);
            fma4(yA[2], hv[2], wa); fma4(yB[2], hv[2], wb);
            fma4(yA[3], hv[3], wa); fma4(yB[3], hv[3], wb);
        }
    }
    // combine 4 k-quarters via LDS (reuse red as float4 buffer)
    float4* pb = reinterpret_cast<float4*>(&red[0][0][0]);   // 3*96*8 float4 = 36 KB
    __syncthreads();
    if (kq > 0) {
        const int base = ((kq - 1) * 96 + dg) * 8;
#pragma unroll
        for (int b = 0; b < 4; ++b) {
            pb[base + b * 2 + 0] = yA[b];
            pb[base + b * 2 + 1] = yB[b];
        }
    }
    __syncthreads();
    if (kq == 0) {
#pragma unroll
        for (int b = 0; b < 4; ++b) {
            float4 rA = yA[b], rB = yB[b];
#pragma unroll
            for (int p = 0; p < 3; ++p) {
                const int base = (p * 96 + dg) * 8 + b * 2;
                const float4 uA = pb[base + 0], uB = pb[base + 1];
                rA.x += uA.x; rA.y += uA.y; rA.z += uA.z; rA.w += uA.w;
                rB.x += uB.x; rB.y += uB.y; rB.z += uB.z; rB.w += uB.w;
            }
            float* o = ysp + (((size_t)hc * B + b) * E + e) * D;
            *reinterpret_cast<float4*>(o + d4a) = rA;
            *reinterpret_cast<float4*>(o + d4b) = rB;
        }
    }
}

// ---------------- K4: reduce ys partials + b2 (float4) ----------------
// grid: B*E*D/4/256 = 48 blocks
__global__ __launch_bounds__(256) void k_ysred(const float* __restrict__ ysp,
                                               const float* __restrict__ b2,
                                               float* __restrict__ ys) {
    const int i4 = blockIdx.x * 256 + threadIdx.x;   // over B*E*D/4
    const int rem4 = i4 % (E * D / 4);
    float4 v = *reinterpret_cast<const float4*>(b2 + (size_t)rem4 * 4);
#pragma unroll 8
    for (int p = 0; p < NHC; ++p) {
        const float4 u = *reinterpret_cast<const float4*>(ysp + (size_t)p * B * E * D + (size_t)i4 * 4);
        v.x += u.x; v.y += u.y; v.z += u.z; v.w += u.w;
    }
    *reinterpret_cast<float4*>(ys + (size_t)i4 * 4) = v;
}

// ---------------- K5: combine ----------------
// grid: B*S/8 = 2048 blocks, 192 threads; block handles 8 s-rows; ys hoisted to regs
__global__ __launch_bounds__(192) void k_combine(const float* __restrict__ logits,
                                                 const float* __restrict__ cmax,
                                                 const float* __restrict__ csum,
                                                 const float* __restrict__ ys,
                                                 float* __restrict__ y) {
    const int blk = blockIdx.x;
    const int b = blk / (S / 8);
    const int s0 = (blk % (S / 8)) * 8;
    const int t = threadIdx.x;
    const int d4 = t * 4;

    float4 ysr[16];
    float cm[16], ci[16];
#pragma unroll
    for (int n = 0; n < 16; ++n) {
        ysr[n] = *reinterpret_cast<const float4*>(ys + ((size_t)b * N + n) * D + d4);
        cm[n] = cmax[b * N + n];
        ci[n] = 1.0f / csum[b * N + n];
    }
#pragma unroll
    for (int r = 0; r < 8; ++r) {
        const int s = s0 + r;
        const float* lrow = logits + ((size_t)b * S + s) * N;
        float4 acc{0, 0, 0, 0};
#pragma unroll
        for (int n = 0; n < 16; ++n) {
            const float cw = __expf(lrow[n] - cm[n]) * ci[n];
            acc.x = fmaf(cw, ysr[n].x, acc.x);
            acc.y = fmaf(cw, ysr[n].y, acc.y);
            acc.z = fmaf(cw, ysr[n].z, acc.z);
            acc.w = fmaf(cw, ysr[n].w, acc.w);
        }
        *reinterpret_cast<float4*>(y + ((size_t)b * S + s) * D + d4) = acc;
    }
}

extern "C" void kernel_launch(void* const* d_in, const int* in_sizes, int n_in,
                              void* d_out, int out_size, void* d_ws, size_t ws_size,
                              hipStream_t stream) {
    const float* x   = (const float*)d_in[0];
    const float* phi = (const float*)d_in[1];
    const float* W1  = (const float*)d_in[2];
    const float* b1  = (const float*)d_in[3];
    const float* W2  = (const float*)d_in[4];
    const float* b2  = (const float*)d_in[5];
    float* y = (float*)d_out;
    float* ws = (float*)d_ws;

    float* logits = ws + OFF_LOG;
    float* pcm    = ws + OFF_PCM;
    float* pcs    = ws + OFF_PCS;
    float* cmax   = ws + OFF_CMAX;
    float* csum   = ws + OFF_CSUM;
    float* xsp    = ws + OFF_XSP;
    float* xs     = ws + OFF_XS;
    float* ysp    = ws + OFF_YSP;
    float* ys     = ws + OFF_YS;

    k_lx<<<B * LPB, 256, 0, stream>>>(x, phi, logits, xsp, pcm, pcs);
    k_xsred_cmerge<<<193, 256, 0, stream>>>(xsp, xs, pcm, pcs, cmax, csum);
    k_ffn<<<E * NHC, 384, 0, stream>>>(xs, W1, b1, W2, ysp);
    k_ysred<<<48, 256, 0, stream>>>(ysp, b2, ys);
    k_combine<<<B * (S / 8), 192, 0, stream>>>(logits, cmax, csum, ys, y);
}

// Round 12
// 140.176 us; speedup vs baseline: 1.0992x; 1.0992x over previous
//
#include <hip/hip_runtime.h>
#include <math.h>

// SoftMoE fp32: B=4,S=4096,D=768,E=16,SLOTS=1,H=3072
constexpr int B = 4, S = 4096, D = 768, E = 16, N = 16, H = 3072;
constexpr int HL = 96;             // h-chunk in fused FFN
constexpr int NHC = H / HL;        // 32
constexpr int LBLK = 32;           // rows per lx block
constexpr int LPB = S / LBLK;      // lx blocks per b = 128

// workspace layout (float offsets)
constexpr size_t OFF_LOG  = 0;                                   // B*S*N
constexpr size_t OFF_PCM  = OFF_LOG + (size_t)B * S * N;         // B*LPB*N
constexpr size_t OFF_PCS  = OFF_PCM + (size_t)B * LPB * N;       // B*LPB*N
constexpr size_t OFF_CMAX = OFF_PCS + (size_t)B * LPB * N;       // B*N
constexpr size_t OFF_CSUM = OFF_CMAX + (size_t)B * N;            // B*N
constexpr size_t OFF_XSP  = OFF_CSUM + (size_t)B * N;            // B*LPB*N*D
constexpr size_t OFF_XS   = OFF_XSP + (size_t)B * LPB * N * D;   // B*N*D
constexpr size_t OFF_YSP  = OFF_XS + (size_t)B * N * D;          // NHC*B*E*D
constexpr size_t OFF_YS   = OFF_YSP + (size_t)NHC * B * E * D;   // B*E*D

typedef float vf4 __attribute__((ext_vector_type(4)));

__device__ __forceinline__ vf4 ntl(const float* p) {
    return __builtin_nontemporal_load(reinterpret_cast<const vf4*>(p));
}
__device__ __forceinline__ void fma4(float4& a, float s, const vf4& w) {
    a.x = fmaf(s, w.x, a.x);
    a.y = fmaf(s, w.y, a.y);
    a.z = fmaf(s, w.z, a.z);
    a.w = fmaf(s, w.w, a.w);
}

// ---------------- K1: fused logits + dispatch softmax + xs partials + cstats ----
// grid: B*LPB = 512 blocks, 256 threads. x rows staged ONCE in LDS; dw stays in LDS.
__global__ __launch_bounds__(256) void k_lx(const float* __restrict__ x,
                                            const float* __restrict__ phi,
                                            float* __restrict__ logits,
                                            float* __restrict__ xsp,
                                            float* __restrict__ pcm,
                                            float* __restrict__ pcs) {
    __shared__ float ph[16][D];          // 48 KB
    __shared__ float xr[LBLK][D + 4];    // 96.5 KB
    __shared__ float dwl[LBLK][16];      // 2 KB
    __shared__ float rm[16][16], rs[16][16];
    const int t = threadIdx.x;
    const int blk = blockIdx.x;
    const int b = blk / LPB;
    const int s0 = (blk % LPB) * LBLK;

#pragma unroll
    for (int i = 0; i < 12; ++i) {
        const int idx = i * 1024 + t * 4;
        const float4 v = *reinterpret_cast<const float4*>(phi + idx);
        const int d0 = idx >> 4;
        const int n0 = idx & 15;
        ph[n0 + 0][d0] = v.x;
        ph[n0 + 1][d0] = v.y;
        ph[n0 + 2][d0] = v.z;
        ph[n0 + 3][d0] = v.w;
    }
    const float* xsrc = x + ((size_t)b * S + s0) * D;
#pragma unroll
    for (int i = 0; i < 24; ++i) {
        const int idx = i * 256 + t;
        const int r = idx / 192, c = idx % 192;
        *reinterpret_cast<float4*>(&xr[r][c * 4]) =
            *reinterpret_cast<const float4*>(xsrc + (size_t)idx * 4);
    }
    __syncthreads();

    const int gid = t >> 4;
    const int ln = t & 15;
    const int r0 = gid * 2, r1 = r0 + 1;

    float4 a0[12], a1[12];
#pragma unroll
    for (int j = 0; j < 12; ++j) {
        a0[j] = *reinterpret_cast<const float4*>(&xr[r0][j * 64 + ln * 4]);
        a1[j] = *reinterpret_cast<const float4*>(&xr[r1][j * 64 + ln * 4]);
    }
    float p0[16], p1[16];
#pragma unroll
    for (int n = 0; n < 16; ++n) {
        float q0 = 0.f, q1 = 0.f;
#pragma unroll
        for (int j = 0; j < 12; ++j) {
            const float4 pv = *reinterpret_cast<const float4*>(&ph[n][j * 64 + ln * 4]);
            q0 = fmaf(a0[j].x, pv.x, q0); q1 = fmaf(a1[j].x, pv.x, q1);
            q0 = fmaf(a0[j].y, pv.y, q0); q1 = fmaf(a1[j].y, pv.y, q1);
            q0 = fmaf(a0[j].z, pv.z, q0); q1 = fmaf(a1[j].z, pv.z, q1);
            q0 = fmaf(a0[j].w, pv.w, q0); q1 = fmaf(a1[j].w, pv.w, q1);
        }
        p0[n] = q0; p1[n] = q1;
    }
#pragma unroll
    for (int m = 1; m < 16; m <<= 1) {
#pragma unroll
        for (int n = 0; n < 16; ++n) {
            p0[n] += __shfl_xor(p0[n], m, 64);
            p1[n] += __shfl_xor(p1[n], m, 64);
        }
    }
    float m0 = -1e30f, m1 = -1e30f;
#pragma unroll
    for (int n = 0; n < 16; ++n) { m0 = fmaxf(m0, p0[n]); m1 = fmaxf(m1, p1[n]); }
    float su0 = 0.f, su1 = 0.f;
#pragma unroll
    for (int n = 0; n < 16; ++n) { su0 += __expf(p0[n] - m0); su1 += __expf(p1[n] - m1); }
    const size_t o0 = ((size_t)b * S + s0 + r0) * N + ln;
    logits[o0] = p0[ln];
    logits[o0 + N] = p1[ln];
    dwl[r0][ln] = __expf(p0[ln] - m0) / su0;
    dwl[r1][ln] = __expf(p1[ln] - m1) / su1;

    const float mm = fmaxf(p0[ln], p1[ln]);
    rm[gid][ln] = mm;
    rs[gid][ln] = __expf(p0[ln] - mm) + __expf(p1[ln] - mm);
    __syncthreads();

    if (t < 16) {
        float M = -1e30f;
#pragma unroll
        for (int g = 0; g < 16; ++g) M = fmaxf(M, rm[g][t]);
        float SS = 0.f;
#pragma unroll
        for (int g = 0; g < 16; ++g) SS += rs[g][t] * __expf(rm[g][t] - M);
        pcm[blk * 16 + t] = M;
        pcs[blk * 16 + t] = SS;
    }

    if (t < 192) {
        const int d4 = t * 4;
        float4 a[16];
#pragma unroll
        for (int n = 0; n < 16; ++n) a[n] = float4{0.f, 0.f, 0.f, 0.f};
#pragma unroll 4
        for (int s = 0; s < LBLK; ++s) {
            const float4 xv = *reinterpret_cast<const float4*>(&xr[s][d4]);
#pragma unroll
            for (int n = 0; n < 16; ++n) {
                const float w = dwl[s][n];
                a[n].x = fmaf(w, xv.x, a[n].x);
                a[n].y = fmaf(w, xv.y, a[n].y);
                a[n].z = fmaf(w, xv.z, a[n].z);
                a[n].w = fmaf(w, xv.w, a[n].w);
            }
        }
        float* o = xsp + (size_t)blk * N * D + d4;
#pragma unroll
        for (int n = 0; n < 16; ++n)
            *reinterpret_cast<float4*>(o + (size_t)n * D) = a[n];
    }
}

// ---------------- K2: reduce xs partials + merge combine stats ----------------
__global__ __launch_bounds__(256) void k_xsred_cmerge(const float* __restrict__ xsp,
                                                      float* __restrict__ xs,
                                                      const float* __restrict__ pcm,
                                                      const float* __restrict__ pcs,
                                                      float* __restrict__ cmax,
                                                      float* __restrict__ csum) {
    const int t = threadIdx.x;
    if (blockIdx.x < 192) {
        const int i = blockIdx.x * 256 + t;      // over B*N*D
        const int b = i / (N * D);
        const int rem = i % (N * D);
        const float* p = xsp + (size_t)b * LPB * N * D + rem;
        float sum = 0.f;
#pragma unroll 4
        for (int c = 0; c < LPB; ++c) sum += p[(size_t)c * N * D];
        xs[i] = sum;
    } else if (t < 64) {
        const int b = t >> 4, n = t & 15;
        float M = -1e30f;
#pragma unroll 8
        for (int c = 0; c < LPB; ++c) M = fmaxf(M, pcm[((size_t)b * LPB + c) * 16 + n]);
        float SS = 0.f;
#pragma unroll 8
        for (int c = 0; c < LPB; ++c)
            SS += pcs[((size_t)b * LPB + c) * 16 + n] * __expf(pcm[((size_t)b * LPB + c) * 16 + n] - M);
        cmax[b * 16 + n] = M;
        csum[b * 16 + n] = SS;
    }
}

// ---------------- K3: fused FFN with EXPLICIT double-buffered load pipelines ----
// grid: E*NHC = 512 blocks, 384 threads. Block = (e, h-chunk of HL=96).
// Each stream phase issues 8 nontemporal float4 loads back-to-back (named A/B
// register buffers, all-static indexing) -> guaranteed >=8 loads in flight/wave.
__global__ __launch_bounds__(384) void k_ffn(const float* __restrict__ xs,
                                             const float* __restrict__ W1,
                                             const float* __restrict__ b1,
                                             const float* __restrict__ W2,
                                             float* __restrict__ ysp) {
    __shared__ __align__(16) float xs_lds[D][4];       // 12 KB (reused as pbuf)
    __shared__ __align__(16) float red_lds[16][HL][4]; // 24 KB
    __shared__ __align__(16) float h_lds[HL][4];       // 1.5 KB

    const int t = threadIdx.x;
    const int e = blockIdx.x / NHC;
    const int hc = blockIdx.x % NHC;
    const int h0 = hc * HL;

    // phase 0: stage xs[:, e, :] transposed -> xs_lds[d][b]
    for (int idx = t; idx < D; idx += 384) {
#pragma unroll
        for (int b = 0; b < 4; ++b)
            xs_lds[idx][b] = xs[((size_t)b * N + e) * D + idx];
    }
    __syncthreads();

    // ---- phase 1: h[b][col] = sum_d xs[b][d] * W1[e][d][h0+col] ----
    // thread: c4 = (t%24)*4 cols, q = t/24 -> 48 d-rows. 6 stages x 8 loads.
    {
        const int c4 = (t % 24) * 4;
        const int q = t / 24;
        const float* w1p = W1 + ((size_t)e * D + (size_t)q * 48) * H + h0 + c4;
        float4 a0{0,0,0,0}, a1{0,0,0,0}, a2{0,0,0,0}, a3{0,0,0,0};
        vf4 bufA[8], bufB[8];
#pragma unroll
        for (int i = 0; i < 8; ++i) bufA[i] = ntl(w1p + (size_t)i * H);

#define P1_STAGE(CUR, NXT, CH, PRE)                                          \
        {                                                                    \
            if (PRE) {                                                       \
                _Pragma("unroll")                                            \
                for (int i = 0; i < 8; ++i)                                  \
                    NXT[i] = ntl(w1p + (size_t)((CH + 1) * 8 + i) * H);      \
            }                                                                \
            _Pragma("unroll")                                                \
            for (int i = 0; i < 8; ++i) {                                    \
                const float* xv = &xs_lds[q * 48 + CH * 8 + i][0];           \
                fma4(a0, xv[0], CUR[i]);                                     \
                fma4(a1, xv[1], CUR[i]);                                     \
                fma4(a2, xv[2], CUR[i]);                                     \
                fma4(a3, xv[3], CUR[i]);                                     \
            }                                                                \
        }
        P1_STAGE(bufA, bufB, 0, 1)
        P1_STAGE(bufB, bufA, 1, 1)
        P1_STAGE(bufA, bufB, 2, 1)
        P1_STAGE(bufB, bufA, 3, 1)
        P1_STAGE(bufA, bufB, 4, 1)
        P1_STAGE(bufB, bufA, 5, 0)
#undef P1_STAGE

        *reinterpret_cast<float4*>(&red_lds[q][c4 + 0][0]) = float4{a0.x, a1.x, a2.x, a3.x};
        *reinterpret_cast<float4*>(&red_lds[q][c4 + 1][0]) = float4{a0.y, a1.y, a2.y, a3.y};
        *reinterpret_cast<float4*>(&red_lds[q][c4 + 2][0]) = float4{a0.z, a1.z, a2.z, a3.z};
        *reinterpret_cast<float4*>(&red_lds[q][c4 + 3][0]) = float4{a0.w, a1.w, a2.w, a3.w};
    }
    __syncthreads();

    // reduce with ALL 384 threads: col = t/4, b = t&3; + bias + exact GELU
    {
        const int col = t >> 2, b = t & 3;
        float s = 0.f;
#pragma unroll
        for (int q = 0; q < 16; ++q) s += red_lds[q][col][b];
        s += b1[(size_t)e * H + h0 + col];
        s = 0.5f * s * (1.0f + erff(s * 0.70710678118654752f));
        h_lds[col][b] = s;
    }
    __syncthreads();

    // ---- phase 2: ys-partial[b][d] = sum_k gelu_h[b][k] * W2[e][h0+k][d] ----
    // thread: kq = t/192 (48 k-rows), dgrp = t%192 (4 d-cols). 6 stages x 8 loads.
    const int dgrp = t % 192;
    const int kq = t / 192;
    float4 y0{0,0,0,0}, y1{0,0,0,0}, y2{0,0,0,0}, y3{0,0,0,0};
    {
        const float* w2p = W2 + ((size_t)e * H + h0 + (size_t)kq * 48) * D + dgrp * 4;
        vf4 bufA[8], bufB[8];
#pragma unroll
        for (int i = 0; i < 8; ++i) bufA[i] = ntl(w2p + (size_t)i * D);

#define P2_STAGE(CUR, NXT, CH, PRE)                                          \
        {                                                                    \
            if (PRE) {                                                       \
                _Pragma("unroll")                                            \
                for (int i = 0; i < 8; ++i)                                  \
                    NXT[i] = ntl(w2p + (size_t)((CH + 1) * 8 + i) * D);      \
            }                                                                \
            _Pragma("unroll")                                                \
            for (int i = 0; i < 8; ++i) {                                    \
                const float* hv = &h_lds[kq * 48 + CH * 8 + i][0];           \
                fma4(y0, hv[0], CUR[i]);                                     \
                fma4(y1, hv[1], CUR[i]);                                     \
                fma4(y2, hv[2], CUR[i]);                                     \
                fma4(y3, hv[3], CUR[i]);                                     \
            }                                                                \
        }
        P2_STAGE(bufA, bufB, 0, 1)
        P2_STAGE(bufB, bufA, 1, 1)
        P2_STAGE(bufA, bufB, 2, 1)
        P2_STAGE(bufB, bufA, 3, 1)
        P2_STAGE(bufA, bufB, 4, 1)
        P2_STAGE(bufB, bufA, 5, 0)
#undef P2_STAGE
    }

    // combine the two k-halves via reused xs_lds
    float4* pbuf = reinterpret_cast<float4*>(&xs_lds[0][0]);   // 192*4 float4 = 12 KB
    __syncthreads();
    if (kq == 1) {
        pbuf[dgrp * 4 + 0] = y0;
        pbuf[dgrp * 4 + 1] = y1;
        pbuf[dgrp * 4 + 2] = y2;
        pbuf[dgrp * 4 + 3] = y3;
    }
    __syncthreads();
    if (kq == 0) {
        float4 r0 = pbuf[dgrp * 4 + 0];
        float4 r1 = pbuf[dgrp * 4 + 1];
        float4 r2 = pbuf[dgrp * 4 + 2];
        float4 r3 = pbuf[dgrp * 4 + 3];
        r0.x += y0.x; r0.y += y0.y; r0.z += y0.z; r0.w += y0.w;
        r1.x += y1.x; r1.y += y1.y; r1.z += y1.z; r1.w += y1.w;
        r2.x += y2.x; r2.y += y2.y; r2.z += y2.z; r2.w += y2.w;
        r3.x += y3.x; r3.y += y3.y; r3.z += y3.z; r3.w += y3.w;
        float* o0 = ysp + (((size_t)hc * B + 0) * E + e) * D + dgrp * 4;
        float* o1 = ysp + (((size_t)hc * B + 1) * E + e) * D + dgrp * 4;
        float* o2 = ysp + (((size_t)hc * B + 2) * E + e) * D + dgrp * 4;
        float* o3 = ysp + (((size_t)hc * B + 3) * E + e) * D + dgrp * 4;
        *reinterpret_cast<float4*>(o0) = r0;
        *reinterpret_cast<float4*>(o1) = r1;
        *reinterpret_cast<float4*>(o2) = r2;
        *reinterpret_cast<float4*>(o3) = r3;
    }
}

// ---------------- K4: reduce ys partials + b2 (float4) ----------------
__global__ __launch_bounds__(256) void k_ysred(const float* __restrict__ ysp,
                                               const float* __restrict__ b2,
                                               float* __restrict__ ys) {
    const int i4 = blockIdx.x * 256 + threadIdx.x;   // over B*E*D/4
    const int rem4 = i4 % (E * D / 4);
    float4 v = *reinterpret_cast<const float4*>(b2 + (size_t)rem4 * 4);
#pragma unroll 8
    for (int p = 0; p < NHC; ++p) {
        const float4 u = *reinterpret_cast<const float4*>(ysp + (size_t)p * B * E * D + (size_t)i4 * 4);
        v.x += u.x; v.y += u.y; v.z += u.z; v.w += u.w;
    }
    *reinterpret_cast<float4*>(ys + (size_t)i4 * 4) = v;
}

// ---------------- K5: combine ----------------
__global__ __launch_bounds__(192) void k_combine(const float* __restrict__ logits,
                                                 const float* __restrict__ cmax,
                                                 const float* __restrict__ csum,
                                                 const float* __restrict__ ys,
                                                 float* __restrict__ y) {
    const int blk = blockIdx.x;
    const int b = blk / (S / 8);
    const int s0 = (blk % (S / 8)) * 8;
    const int t = threadIdx.x;
    const int d4 = t * 4;

    float4 ysr[16];
    float cm[16], ci[16];
#pragma unroll
    for (int n = 0; n < 16; ++n) {
        ysr[n] = *reinterpret_cast<const float4*>(ys + ((size_t)b * N + n) * D + d4);
        cm[n] = cmax[b * N + n];
        ci[n] = 1.0f / csum[b * N + n];
    }
#pragma unroll
    for (int r = 0; r < 8; ++r) {
        const int s = s0 + r;
        const float* lrow = logits + ((size_t)b * S + s) * N;
        float4 acc{0, 0, 0, 0};
#pragma unroll
        for (int n = 0; n < 16; ++n) {
            const float cw = __expf(lrow[n] - cm[n]) * ci[n];
            acc.x = fmaf(cw, ysr[n].x, acc.x);
            acc.y = fmaf(cw, ysr[n].y, acc.y);
            acc.z = fmaf(cw, ysr[n].z, acc.z);
            acc.w = fmaf(cw, ysr[n].w, acc.w);
        }
        *reinterpret_cast<float4*>(y + ((size_t)b * S + s) * D + d4) = acc;
    }
}

extern "C" void kernel_launch(void* const* d_in, const int* in_sizes, int n_in,
                              void* d_out, int out_size, void* d_ws, size_t ws_size,
                              hipStream_t stream) {
    const float* x   = (const float*)d_in[0];
    const float* phi = (const float*)d_in[1];
    const float* W1  = (const float*)d_in[2];
    const float* b1  = (const float*)d_in[3];
    const float* W2  = (const float*)d_in[4];
    const float* b2  = (const float*)d_in[5];
    float* y = (float*)d_out;
    float* ws = (float*)d_ws;

    float* logits = ws + OFF_LOG;
    float* pcm    = ws + OFF_PCM;
    float* pcs    = ws + OFF_PCS;
    float* cmax   = ws + OFF_CMAX;
    float* csum   = ws + OFF_CSUM;
    float* xsp    = ws + OFF_XSP;
    float* xs     = ws + OFF_XS;
    float* ysp    = ws + OFF_YSP;
    float* ys     = ws + OFF_YS;

    k_lx<<<B * LPB, 256, 0, stream>>>(x, phi, logits, xsp, pcm, pcs);
    k_xsred_cmerge<<<193, 256, 0, stream>>>(xsp, xs, pcm, pcs, cmax, csum);
    k_ffn<<<E * NHC, 384, 0, stream>>>(xs, W1, b1, W2, ysp);
    k_ysred<<<48, 256, 0, stream>>>(ysp, b2, ys);
    k_combine<<<B * (S / 8), 192, 0, stream>>>(logits, cmax, csum, ys, y);
}